// Round 17
// baseline (210.785 us; speedup 1.0000x reference)
//
#include <hip/hip_runtime.h>
#include <hip/hip_bf16.h>

typedef short bf16x8 __attribute__((ext_vector_type(8)));
typedef float f32x4 __attribute__((ext_vector_type(4)));
typedef unsigned short u16;

#define B_    32
#define L_    8192
#define C_    8
#define P_    512
#define D_    256
#define SED_  16
#define CED_  8
#define INDIM 2576
#define NROWS (B_ * P_)

#define TB_WTS 0
#define TB_IWT 1
#define TB_SYS 2
#define TB_GW1 3
#define TB_BWB 4
#define TB_CH0 5
#define TB_W2G 10
#define TB_B2  11

#define NPREP 154u

__device__ __forceinline__ u16 f2bf(float f) {
    __hip_bfloat16 h = __float2bfloat16(f);
    return *reinterpret_cast<u16*>(&h);
}

// ================================================================= mega kernel
// Node 2 of 2. Phase A: prep (blocks 0..153). Manual device-scope flag
// barrier (all 512 blocks co-resident: 23.3 KB LDS, <=128 VGPR, 16 waves/CU).
// Phase B: r10 k_main verbatim (H tile aliased onto As, r4-verified).
__global__ __launch_bounds__(512, 4) void k_mega(
    const float* __restrict__ x, const float* __restrict__ fs,
    const float* __restrict__ ce, const float* __restrict__ se,
    const float* __restrict__ g1, const float* __restrict__ bb1,
    const float* __restrict__ W1, const float* __restrict__ b1,
    const float* __restrict__ g2, const float* __restrict__ bb2,
    const float* __restrict__ W2, const float* __restrict__ b2,
    const int* __restrict__ sLp, const int* __restrict__ sCp,
    const int* __restrict__ ctm, const int* __restrict__ sysid,
    u16* __restrict__ wdt, u16* __restrict__ w2t,
    float* __restrict__ tabF, unsigned* __restrict__ flag,
    float* __restrict__ scal, float* __restrict__ out)
{
    __shared__ __attribute__((aligned(16))) u16 As[8 * 32 * 40];  // 20480 B (A-scratch | A tile | H tile)
    __shared__ __attribute__((aligned(16))) float ps1[32 * 8], ps2[32 * 8];
    __shared__ float rmu[32], rrs[32], rsl[32];
    __shared__ int   rsc[32];
    __shared__ float rmu2[32], rrs2[32];

    int t = threadIdx.x;
    int c = blockIdx.x;

    // =========================== phase A: prep (r9-verified; blocks 0..153)
    {
        float* sg = (float*)As;
        if (c < 81) {
            float* sb = sg + 32;
            float* st = sb + 32;
            float (*cs5)[32] = (float(*)[32])(st + 32);
            int sid = sysid[0];
            int k0 = c * 32;
            int kend = INDIM - k0; if (kend > 32) kend = 32;
            int type = (k0 < 256) ? 0 : (k0 < 512) ? 1 : (k0 < 2560) ? 2 : 3;
            if (t < 256) {
                int n = t;
                if (n < kend) {
                    int k = k0 + n;
                    sg[n] = g1[k]; sb[n] = bb1[k];
                    float xv = 0.f;
                    if (type == 1) xv = (float)((k - 256) >> 2);
                    if (type == 3) xv = se[sid * SED_ + (k - 2560)];
                    st[n] = xv;
                }
                if (type == 2 && n < 160) {
                    int s = n >> 5, kt = n & 31, k = k0 + kt;
                    cs5[s][kt] = ce[ctm[sid * 20 + s + ((k >> 3) & 3)] * CED_ + (k & 7)];
                }
            }
            __syncthreads();
            if (t < 256) {
                int n = t;
                float pg = 0, pb = 0, ai = 0, as_ = 0;
                float a5 = 0, a6 = 0, a7 = 0, a8 = 0, a9 = 0;
#pragma unroll 8
                for (int kt = 0; kt < kend; ++kt) {
                    float wv = W1[(size_t)(k0 + kt) * D_ + n];
                    float gw = sg[kt] * wv;
                    pg += gw; pb += sb[kt] * wv;
                    if (type == 1) ai += st[kt] * gw;
                    if (type == 2) {
                        a5 += cs5[0][kt] * gw; a6 += cs5[1][kt] * gw; a7 += cs5[2][kt] * gw;
                        a8 += cs5[3][kt] * gw; a9 += cs5[4][kt] * gw;
                    }
                    if (type == 3) as_ += st[kt] * gw;
                }
                atomicAdd(&tabF[TB_GW1 * 256 + n], pg);
                atomicAdd(&tabF[TB_BWB * 256 + n], pb);
                if (type == 1) {
                    atomicAdd(&tabF[TB_WTS * 256 + n], pg);
                    atomicAdd(&tabF[TB_IWT * 256 + n], ai);
                }
                if (type == 2) {
                    atomicAdd(&tabF[(TB_CH0 + 0) * 256 + n], a5);
                    atomicAdd(&tabF[(TB_CH0 + 1) * 256 + n], a6);
                    atomicAdd(&tabF[(TB_CH0 + 2) * 256 + n], a7);
                    atomicAdd(&tabF[(TB_CH0 + 3) * 256 + n], a8);
                    atomicAdd(&tabF[(TB_CH0 + 4) * 256 + n], a9);
                }
                if (type == 3) atomicAdd(&tabF[TB_SYS * 256 + n], as_);
            }
        } else if (c < 89) {
            float* sb = sg + 32;
            int k0 = (c - 81) * 32;
            if (t < 32) { sg[t] = g2[k0 + t]; sb[t] = bb2[k0 + t]; }
            __syncthreads();
            if (t < 256) {
                int n = t;
                float pg = 0, pb = 0;
#pragma unroll 8
                for (int kt = 0; kt < 32; ++kt) {
                    float wv = W2[(size_t)(k0 + kt) * D_ + n];
                    pg += sg[kt] * wv; pb += sb[kt] * wv;
                }
                atomicAdd(&tabF[TB_W2G * 256 + n], pg);
                atomicAdd(&tabF[TB_B2  * 256 + n], pb);
            }
        } else if (c < 153) {
            // fragment-order weight writer: flat[((cg*8+kk)*64+lane)*8+e]
            if (t < 256) {
                int n = t;
                int fb = c - 89;
                const float* W = (fb < 32) ? W1 : W2;
                const float* g = (fb < 32) ? g1 : g2;
                u16* dst = (fb < 32) ? wdt : w2t;
                int cid = (fb & 31) * 256 + n;
                int l = cid & 63;
                int col = ((cid >> 9) << 4) + (l & 15);
                int kb = (((cid >> 6) & 7) << 5) + ((l >> 4) << 3);
                bf16x8 v;
#pragma unroll
                for (int e = 0; e < 8; ++e)
                    v[e] = (short)f2bf(g[kb + e] * W[(size_t)(kb + e) * D_ + col]);
                *(bf16x8*)&dst[(size_t)cid * 8] = v;
            }
        } else if (c == 153) {
            float* sv = sg;
            float* sqv = sv + 176;
            int sid = sysid[0];
            if (t < 160) {
                int s5 = t >> 5, s = t & 31;
                float v = ce[ctm[sid * 20 + s5 + (s >> 3)] * CED_ + (s & 7)];
                sv[t] = v; sqv[t] = v * v;
            } else if (t < 176) {
                float v = se[sid * SED_ + (t - 160)];
                sv[t] = v; sqv[t] = v * v;
            }
            __syncthreads();
            if (t < 5) {
                float a = 0, bq = 0;
                for (int j2 = 0; j2 < 32; ++j2) { a += sv[t * 32 + j2]; bq += sqv[t * 32 + j2]; }
                scal[t] = a; scal[5 + t] = bq;
            }
            if (t == 10) {
                float a = 0, bq = 0;
                for (int j2 = 0; j2 < 16; ++j2) { a += sv[160 + j2]; bq += sqv[160 + j2]; }
                scal[10] = a; scal[11] = bq;
            }
            if (t >= 12 && t < 16) scal[t] = 0.f;
        }
    }

    // =========================== manual grid barrier (device-scope)
    if (c < (int)NPREP) {
        __threadfence();               // release: prep writes visible device-wide
        __syncthreads();
        if (t == 0)
            __hip_atomic_fetch_add(flag, 1u, __ATOMIC_RELEASE, __HIP_MEMORY_SCOPE_AGENT);
    }
    if (t == 0) {
        unsigned it = 0;
        while (__hip_atomic_load(flag, __ATOMIC_ACQUIRE, __HIP_MEMORY_SCOPE_AGENT) < NPREP
               && ++it < (1u << 22)) {
            __builtin_amdgcn_s_sleep(2);   // timeout: wrong-answer, never hang
        }
    }
    __syncthreads();
    __threadfence();                   // acquire: invalidate stale L1/L2 lines

    // =========================== phase B: r10 k_main (H aliased onto As)
    int tile = ((blockIdx.x & 7) << 6) + (blockIdx.x >> 3);   // XCD-bijective
    int r0 = tile * 32;
    int b = r0 >> 9;
    float fsinv = 1.0f / fs[b];

    int row = t >> 4, u = t & 15;
    int w = t >> 6, lane = t & 63, l15 = lane & 15, hi = lane >> 4;
    int col0 = w * 32;

    int r = r0 + row;
    int sL = sLp[r], sC = sCp[r];

    // GEMM1 B preload (fragment-order, 1 KB/wave coalesced)
    bf16x8 bA[8], bB[8];
    {
        const u16* p0 = &wdt[(size_t)(((2 * w) * 8) * 64 + lane) * 8];
        const u16* p1 = &wdt[(size_t)(((2 * w + 1) * 8) * 64 + lane) * 8];
#pragma unroll
        for (int kk = 0; kk < 8; ++kk) {
            bA[kk] = *(const bf16x8*)(p0 + (size_t)kk * 512);
            bB[kk] = *(const bf16x8*)(p1 + (size_t)kk * 512);
        }
    }

    // gather + LN1 stats (16 threads/row, shfl reduce)
    {
        const float* xb = x + ((size_t)b << 16);
        float s = 0.f, sq = 0.f;
#pragma unroll
        for (int i2 = 0; i2 < 4; ++i2) {
            int i = i2 * 16 + u;
            const float* px = xb + (size_t)(sL + i) * 8 + sC;
            f32x4 v;
            __builtin_memcpy(&v, px, 16);
            s += v[0] + v[1] + v[2] + v[3];
            sq += v[0] * v[0] + v[1] * v[1] + v[2] * v[2] + v[3] * v[3];
            *(ushort4*)&As[(i2 * 2 + (u >> 3)) * 1280 + row * 40 + (u & 7) * 4] =
                make_ushort4(f2bf(v[0]), f2bf(v[1]), f2bf(v[2]), f2bf(v[3]));
        }
        s += __shfl_xor(s, 1); s += __shfl_xor(s, 2); s += __shfl_xor(s, 4); s += __shfl_xor(s, 8);
        sq += __shfl_xor(sq, 1); sq += __shfl_xor(sq, 2); sq += __shfl_xor(sq, 4); sq += __shfl_xor(sq, 8);
        if (u == 0) {
            float sLf = (float)sL;
            float Ss = s + 4.f * fsinv * (64.f * sLf + 2016.f) + 64.f * scal[sC] + scal[10];
            float Sq = sq + 4.f * fsinv * fsinv * (64.f * sLf * sLf + 4032.f * sLf + 85344.f)
                     + 64.f * scal[5 + sC] + scal[11];
            float mu = Ss * (1.f / (float)INDIM);
            float var = Sq * (1.f / (float)INDIM) - mu * mu;
            rmu[row] = mu; rrs[row] = rsqrtf(var + 1e-5f);
            rsl[row] = sLf; rsc[row] = sC;
        }
    }
    __syncthreads();                                           // B1

    // GEMM1 (K=256): LDS-A + in-reg B
    f32x4 acc[2][2];
#pragma unroll
    for (int fm = 0; fm < 2; ++fm)
#pragma unroll
        for (int fn = 0; fn < 2; ++fn) acc[fm][fn] = (f32x4){0.f, 0.f, 0.f, 0.f};
#pragma unroll
    for (int kk = 0; kk < 8; ++kk) {
        bf16x8 a0 = *(const bf16x8*)&As[kk * 1280 + l15 * 40 + hi * 8];
        bf16x8 a1 = *(const bf16x8*)&As[kk * 1280 + (16 + l15) * 40 + hi * 8];
        acc[0][0] = __builtin_amdgcn_mfma_f32_16x16x32_bf16(a0, bA[kk], acc[0][0], 0, 0, 0);
        acc[1][0] = __builtin_amdgcn_mfma_f32_16x16x32_bf16(a1, bA[kk], acc[1][0], 0, 0, 0);
        acc[0][1] = __builtin_amdgcn_mfma_f32_16x16x32_bf16(a0, bB[kk], acc[0][1], 0, 0, 0);
        acc[1][1] = __builtin_amdgcn_mfma_f32_16x16x32_bf16(a1, bB[kk], acc[1][1], 0, 0, 0);
    }
    __syncthreads();                                           // B1.5: As reads done

    // GEMM2 B preload (lands under epilogue-1 VALU)
    {
        const u16* p0 = &w2t[(size_t)(((2 * w) * 8) * 64 + lane) * 8];
        const u16* p1 = &w2t[(size_t)(((2 * w + 1) * 8) * 64 + lane) * 8];
#pragma unroll
        for (int kk = 0; kk < 8; ++kk) {
            bA[kk] = *(const bf16x8*)(p0 + (size_t)kk * 512);
            bB[kk] = *(const bf16x8*)(p1 + (size_t)kk * 512);
        }
    }

    // epilogue1: LN1-fold + SiLU -> H (into As), LN2 partials; tables from L2
    {
        float p_s[2][4] = {}, p_q[2][4] = {};
#pragma unroll
        for (int fn = 0; fn < 2; ++fn) {
            int colf = col0 + fn * 16 + l15;
            float vwts = tabF[TB_WTS * 256 + colf];
            float viwt = tabF[TB_IWT * 256 + colf];
            float vsys = tabF[TB_SYS * 256 + colf];
            float vgw1 = tabF[TB_GW1 * 256 + colf];
            float vbwb = tabF[TB_BWB * 256 + colf] + b1[colf];
            const float* tch = &tabF[TB_CH0 * 256 + colf];
#pragma unroll
            for (int fm = 0; fm < 2; ++fm)
#pragma unroll
                for (int j = 0; j < 4; ++j) {
                    int rr = fm * 16 + hi * 4 + j;
                    float fw = acc[fm][fn][j]
                             + fsinv * (rsl[rr] * vwts + viwt)
                             + tch[rsc[rr] * 256] + vsys;
                    float o1 = rrs[rr] * (fw - rmu[rr] * vgw1) + vbwb;
                    float h = o1 / (1.f + __expf(-o1));
                    p_s[fm][j] += h; p_q[fm][j] += h * h;
                    As[w * 1280 + rr * 40 + fn * 16 + l15] = f2bf(h);
                }
        }
#pragma unroll
        for (int fm = 0; fm < 2; ++fm)
#pragma unroll
            for (int j = 0; j < 4; ++j) {
                float s = p_s[fm][j], q = p_q[fm][j];
                s += __shfl_xor(s, 1); s += __shfl_xor(s, 2); s += __shfl_xor(s, 4); s += __shfl_xor(s, 8);
                q += __shfl_xor(q, 1); q += __shfl_xor(q, 2); q += __shfl_xor(q, 4); q += __shfl_xor(q, 8);
                if (l15 == 0) {
                    int rr = fm * 16 + hi * 4 + j;
                    ps1[rr * 8 + w] = s; ps2[rr * 8 + w] = q;
                }
            }
    }
    __syncthreads();                                           // B2

    // stats2 (t<32) overlapped with GEMM2
    if (t < 32) {
        f32x4 a = *(f32x4*)&ps1[t * 8], bb = *(f32x4*)&ps1[t * 8 + 4];
        f32x4 cq = *(f32x4*)&ps2[t * 8], dq = *(f32x4*)&ps2[t * 8 + 4];
        float ts = a[0] + a[1] + a[2] + a[3] + bb[0] + bb[1] + bb[2] + bb[3];
        float tq = cq[0] + cq[1] + cq[2] + cq[3] + dq[0] + dq[1] + dq[2] + dq[3];
        float mu2 = ts * (1.f / 256.f);
        float var2 = tq * (1.f / 256.f) - mu2 * mu2;
        rmu2[t] = mu2; rrs2[t] = rsqrtf(var2 + 1e-5f);
    }

    // GEMM2 (K=256): H from As + in-reg B
    f32x4 acc2[2][2];
#pragma unroll
    for (int fm = 0; fm < 2; ++fm)
#pragma unroll
        for (int fn = 0; fn < 2; ++fn) acc2[fm][fn] = (f32x4){0.f, 0.f, 0.f, 0.f};
#pragma unroll
    for (int kk = 0; kk < 8; ++kk) {
        bf16x8 a0 = *(const bf16x8*)&As[kk * 1280 + l15 * 40 + hi * 8];
        bf16x8 a1 = *(const bf16x8*)&As[kk * 1280 + (16 + l15) * 40 + hi * 8];
        acc2[0][0] = __builtin_amdgcn_mfma_f32_16x16x32_bf16(a0, bA[kk], acc2[0][0], 0, 0, 0);
        acc2[1][0] = __builtin_amdgcn_mfma_f32_16x16x32_bf16(a1, bA[kk], acc2[1][0], 0, 0, 0);
        acc2[0][1] = __builtin_amdgcn_mfma_f32_16x16x32_bf16(a0, bB[kk], acc2[0][1], 0, 0, 0);
        acc2[1][1] = __builtin_amdgcn_mfma_f32_16x16x32_bf16(a1, bB[kk], acc2[1][1], 0, 0, 0);
    }
    __syncthreads();                                           // B3

    // epilogue2: LN2-fold -> out
#pragma unroll
    for (int fn = 0; fn < 2; ++fn) {
        int colf = col0 + fn * 16 + l15;
        float vW2G = tabF[TB_W2G * 256 + colf];
        float vB2  = tabF[TB_B2  * 256 + colf] + b2[colf];
#pragma unroll
        for (int fm = 0; fm < 2; ++fm)
#pragma unroll
            for (int j = 0; j < 4; ++j) {
                int rr = fm * 16 + hi * 4 + j;
                float o = rrs2[rr] * (acc2[fm][fn][j] - rmu2[rr] * vW2G) + vB2;
                out[(size_t)(r0 + rr) * 256 + colf] = o;
            }
    }
}

// ================================================================= launch
extern "C" void kernel_launch(void* const* d_in, const int* in_sizes, int n_in,
                              void* d_out, int out_size, void* d_ws, size_t ws_size,
                              hipStream_t stream) {
    const float* x   = (const float*)d_in[0];
    const float* fs  = (const float*)d_in[1];
    const float* ce  = (const float*)d_in[2];
    const float* se  = (const float*)d_in[3];
    const float* g1  = (const float*)d_in[4];
    const float* bb1 = (const float*)d_in[5];
    const float* W1  = (const float*)d_in[6];
    const float* b1  = (const float*)d_in[7];
    const float* g2  = (const float*)d_in[8];
    const float* bb2 = (const float*)d_in[9];
    const float* W2  = (const float*)d_in[10];
    const float* b2  = (const float*)d_in[11];
    const int* sL    = (const int*)d_in[12];
    const int* sC    = (const int*)d_in[13];
    const int* ctm   = (const int*)d_in[14];
    const int* sysid = (const int*)d_in[15];
    float* out = (float*)d_out;

    char* ws = (char*)d_ws;
    u16*      wdt  = (u16*)(ws + 0);           // 131072 B (fragment order)
    u16*      w2t  = (u16*)(ws + 131072);      // 131072 B (fragment order)
    float*    tabF = (float*)(ws + 262144);    // 12288 B  (zeroed per call)
    unsigned* flag = (unsigned*)(ws + 274432); // 4 B      (zeroed per call)
    float*    scal = (float*)(ws + 274448);    // 64 B

    hipMemsetAsync(ws + 262144, 0, 12292, stream);   // tabF + flag
    k_mega<<<dim3(512), dim3(512), 0, stream>>>(
        x, fs, ce, se, g1, bb1, W1, b1, g2, bb2, W2, b2,
        sL, sC, ctm, sysid, wdt, w2t, tabF, flag, scal, out);
}

// Round 18
// 39.988 us; speedup vs baseline: 5.2712x; 5.2712x over previous
//
#include <hip/hip_runtime.h>
#include <hip/hip_bf16.h>

typedef short bf16x8 __attribute__((ext_vector_type(8)));
typedef float f32x4 __attribute__((ext_vector_type(4)));
typedef unsigned short u16;

#define B_    32
#define L_    8192
#define C_    8
#define P_    512
#define D_    256
#define SED_  16
#define CED_  8
#define INDIM 2576
#define NROWS (B_ * P_)

#define TB_WTS 0
#define TB_IWT 1
#define TB_SYS 2
#define TB_GW1 3
#define TB_BWB 4
#define TB_CH0 5
#define TB_W2G 10
#define TB_B2  11

__device__ __forceinline__ u16 f2bf(float f) {
    __hip_bfloat16 h = __float2bfloat16(f);
    return *reinterpret_cast<u16*>(&h);
}

// ================================================================= zero tabF
__global__ __launch_bounds__(256) void k_zero(float* __restrict__ tabF) {
    tabF[blockIdx.x * 256 + threadIdx.x] = 0.f;
}

// ================================================================= prep (verified r9/r10)
__global__ __launch_bounds__(256) void k_prep(
    const float* __restrict__ W1, const float* __restrict__ W2,
    const float* __restrict__ g1, const float* __restrict__ bb1,
    const float* __restrict__ g2, const float* __restrict__ bb2,
    const float* __restrict__ ce, const float* __restrict__ se,
    const int* __restrict__ ctm, const int* __restrict__ sysid,
    u16* __restrict__ wdt, u16* __restrict__ w2t,
    float* __restrict__ tabF, float* __restrict__ scal)
{
    __shared__ __attribute__((aligned(16))) char sh[8320];
    int c = blockIdx.x, n = threadIdx.x;

    if (c < 81) {
        float* sg = (float*)sh;
        float* sb = sg + 32;
        float* st = sb + 32;
        float (*cs5)[32] = (float(*)[32])(st + 32);
        int sid = sysid[0];
        int k0 = c * 32;
        int kend = INDIM - k0; if (kend > 32) kend = 32;
        int type = (k0 < 256) ? 0 : (k0 < 512) ? 1 : (k0 < 2560) ? 2 : 3;
        if (n < kend) {
            int k = k0 + n;
            sg[n] = g1[k]; sb[n] = bb1[k];
            float xv = 0.f;
            if (type == 1) xv = (float)((k - 256) >> 2);
            if (type == 3) xv = se[sid * SED_ + (k - 2560)];
            st[n] = xv;
        }
        if (type == 2 && n < 160) {
            int s = n >> 5, kt = n & 31, k = k0 + kt;
            cs5[s][kt] = ce[ctm[sid * 20 + s + ((k >> 3) & 3)] * CED_ + (k & 7)];
        }
        __syncthreads();
        float pg = 0, pb = 0, ai = 0, as_ = 0;
        float a5 = 0, a6 = 0, a7 = 0, a8 = 0, a9 = 0;
#pragma unroll 8
        for (int kt = 0; kt < kend; ++kt) {
            float wv = W1[(size_t)(k0 + kt) * D_ + n];
            float gw = sg[kt] * wv;
            pg += gw; pb += sb[kt] * wv;
            if (type == 1) ai += st[kt] * gw;
            if (type == 2) {
                a5 += cs5[0][kt] * gw; a6 += cs5[1][kt] * gw; a7 += cs5[2][kt] * gw;
                a8 += cs5[3][kt] * gw; a9 += cs5[4][kt] * gw;
            }
            if (type == 3) as_ += st[kt] * gw;
        }
        atomicAdd(&tabF[TB_GW1 * 256 + n], pg);
        atomicAdd(&tabF[TB_BWB * 256 + n], pb);
        if (type == 1) {
            atomicAdd(&tabF[TB_WTS * 256 + n], pg);
            atomicAdd(&tabF[TB_IWT * 256 + n], ai);
        }
        if (type == 2) {
            atomicAdd(&tabF[(TB_CH0 + 0) * 256 + n], a5);
            atomicAdd(&tabF[(TB_CH0 + 1) * 256 + n], a6);
            atomicAdd(&tabF[(TB_CH0 + 2) * 256 + n], a7);
            atomicAdd(&tabF[(TB_CH0 + 3) * 256 + n], a8);
            atomicAdd(&tabF[(TB_CH0 + 4) * 256 + n], a9);
        }
        if (type == 3) atomicAdd(&tabF[TB_SYS * 256 + n], as_);
    } else if (c < 89) {
        float* sg = (float*)sh;
        float* sb = sg + 32;
        int k0 = (c - 81) * 32;
        if (n < 32) { sg[n] = g2[k0 + n]; sb[n] = bb2[k0 + n]; }
        __syncthreads();
        float pg = 0, pb = 0;
#pragma unroll 8
        for (int kt = 0; kt < 32; ++kt) {
            float wv = W2[(size_t)(k0 + kt) * D_ + n];
            pg += sg[kt] * wv; pb += sb[kt] * wv;
        }
        atomicAdd(&tabF[TB_W2G * 256 + n], pg);
        atomicAdd(&tabF[TB_B2  * 256 + n], pb);
    } else if (c < 153) {
        // fragment-order weight writer: flat[((cg*8+kk)*64+lane)*8+e]
        int fb = c - 89;
        const float* W = (fb < 32) ? W1 : W2;
        const float* g = (fb < 32) ? g1 : g2;
        u16* dst = (fb < 32) ? wdt : w2t;
        int cid = (fb & 31) * 256 + n;
        int l = cid & 63;
        int col = ((cid >> 9) << 4) + (l & 15);
        int kb = (((cid >> 6) & 7) << 5) + ((l >> 4) << 3);
        bf16x8 v;
#pragma unroll
        for (int e = 0; e < 8; ++e)
            v[e] = (short)f2bf(g[kb + e] * W[(size_t)(kb + e) * D_ + col]);
        *(bf16x8*)&dst[(size_t)cid * 8] = v;
    } else {
        float* sv = (float*)sh;
        float* sqv = sv + 176;
        int sid = sysid[0];
        if (n < 160) {
            int s5 = n >> 5, s = n & 31;
            float v = ce[ctm[sid * 20 + s5 + (s >> 3)] * CED_ + (s & 7)];
            sv[n] = v; sqv[n] = v * v;
        } else if (n < 176) {
            float v = se[sid * SED_ + (n - 160)];
            sv[n] = v; sqv[n] = v * v;
        }
        __syncthreads();
        if (n < 5) {
            float a = 0, bq = 0;
            for (int j2 = 0; j2 < 32; ++j2) { a += sv[n * 32 + j2]; bq += sqv[n * 32 + j2]; }
            scal[n] = a; scal[5 + n] = bq;
        }
        if (n == 10) {
            float a = 0, bq = 0;
            for (int j2 = 0; j2 < 16; ++j2) { a += sv[160 + j2]; bq += sqv[160 + j2]; }
            scal[10] = a; scal[11] = bq;
        }
        if (n >= 12 && n < 16) scal[n] = 0.f;
    }
}

// ================================================================= main fused
// M=32, 512 threads, grid 512 (2 blocks/CU). B preloaded to regs from
// fragment-order weights (coalesced). Epilogue tables direct from L2 after
// GEMM1. 3 barriers. [best measured: 39.97 us total]
__global__ __launch_bounds__(512, 4) void k_main(
    const float* __restrict__ x, const float* __restrict__ fs,
    const int* __restrict__ sLp, const int* __restrict__ sCp,
    const u16* __restrict__ wdt, const u16* __restrict__ w2t,
    const float* __restrict__ tabF, const float* __restrict__ scal,
    const float* __restrict__ b1, const float* __restrict__ b2,
    float* __restrict__ out)
{
    __shared__ __attribute__((aligned(16))) u16 As[8 * 32 * 40];  // 20.5 KB
    __shared__ __attribute__((aligned(16))) u16 Hs[8 * 32 * 40];  // 20.5 KB
    __shared__ __attribute__((aligned(16))) float ps1[32 * 8], ps2[32 * 8];
    __shared__ float rmu[32], rrs[32], rsl[32];
    __shared__ int   rsc[32];
    __shared__ float rmu2[32], rrs2[32];

    int t = threadIdx.x;
    int tile = ((blockIdx.x & 7) << 6) + (blockIdx.x >> 3);   // XCD-bijective
    int r0 = tile * 32;
    int b = r0 >> 9;
    float fsinv = 1.0f / fs[b];

    int row = t >> 4, u = t & 15;
    int w = t >> 6, lane = t & 63, l15 = lane & 15, hi = lane >> 4;
    int col0 = w * 32;

    int r = r0 + row;
    int sL = sLp[r], sC = sCp[r];

    // GEMM1 B preload: 16 independent coalesced loads (1 KB/wave each),
    // issued before the gather so the latencies overlap.
    bf16x8 bA[8], bB[8];
    {
        const u16* p0 = &wdt[(size_t)(((2 * w) * 8) * 64 + lane) * 8];
        const u16* p1 = &wdt[(size_t)(((2 * w + 1) * 8) * 64 + lane) * 8];
#pragma unroll
        for (int kk = 0; kk < 8; ++kk) {
            bA[kk] = *(const bf16x8*)(p0 + (size_t)kk * 512);
            bB[kk] = *(const bf16x8*)(p1 + (size_t)kk * 512);
        }
    }

    // ---- gather + LN1 stats (16 threads/row, shfl reduce)
    {
        const float* xb = x + ((size_t)b << 16);
        float s = 0.f, sq = 0.f;
#pragma unroll
        for (int i2 = 0; i2 < 4; ++i2) {
            int i = i2 * 16 + u;
            const float* px = xb + (size_t)(sL + i) * 8 + sC;
            f32x4 v;
            __builtin_memcpy(&v, px, 16);
            s += v[0] + v[1] + v[2] + v[3];
            sq += v[0] * v[0] + v[1] * v[1] + v[2] * v[2] + v[3] * v[3];
            *(ushort4*)&As[(i2 * 2 + (u >> 3)) * 1280 + row * 40 + (u & 7) * 4] =
                make_ushort4(f2bf(v[0]), f2bf(v[1]), f2bf(v[2]), f2bf(v[3]));
        }
        s += __shfl_xor(s, 1); s += __shfl_xor(s, 2); s += __shfl_xor(s, 4); s += __shfl_xor(s, 8);
        sq += __shfl_xor(sq, 1); sq += __shfl_xor(sq, 2); sq += __shfl_xor(sq, 4); sq += __shfl_xor(sq, 8);
        if (u == 0) {
            float sLf = (float)sL;
            float Ss = s + 4.f * fsinv * (64.f * sLf + 2016.f) + 64.f * scal[sC] + scal[10];
            float Sq = sq + 4.f * fsinv * fsinv * (64.f * sLf * sLf + 4032.f * sLf + 85344.f)
                     + 64.f * scal[5 + sC] + scal[11];
            float mu = Ss * (1.f / (float)INDIM);
            float var = Sq * (1.f / (float)INDIM) - mu * mu;
            rmu[row] = mu; rrs[row] = rsqrtf(var + 1e-5f);
            rsl[row] = sLf; rsc[row] = sC;
        }
    }
    __syncthreads();                                           // B1

    // ---- GEMM1 (K=256): LDS-A + in-reg B
    f32x4 acc[2][2];
#pragma unroll
    for (int fm = 0; fm < 2; ++fm)
#pragma unroll
        for (int fn = 0; fn < 2; ++fn) acc[fm][fn] = (f32x4){0.f, 0.f, 0.f, 0.f};
#pragma unroll
    for (int kk = 0; kk < 8; ++kk) {
        bf16x8 a0 = *(const bf16x8*)&As[kk * 1280 + l15 * 40 + hi * 8];
        bf16x8 a1 = *(const bf16x8*)&As[kk * 1280 + (16 + l15) * 40 + hi * 8];
        acc[0][0] = __builtin_amdgcn_mfma_f32_16x16x32_bf16(a0, bA[kk], acc[0][0], 0, 0, 0);
        acc[1][0] = __builtin_amdgcn_mfma_f32_16x16x32_bf16(a1, bA[kk], acc[1][0], 0, 0, 0);
        acc[0][1] = __builtin_amdgcn_mfma_f32_16x16x32_bf16(a0, bB[kk], acc[0][1], 0, 0, 0);
        acc[1][1] = __builtin_amdgcn_mfma_f32_16x16x32_bf16(a1, bB[kk], acc[1][1], 0, 0, 0);
    }

    // ---- GEMM2 B preload (lands under epilogue-1 VALU)
    {
        const u16* p0 = &w2t[(size_t)(((2 * w) * 8) * 64 + lane) * 8];
        const u16* p1 = &w2t[(size_t)(((2 * w + 1) * 8) * 64 + lane) * 8];
#pragma unroll
        for (int kk = 0; kk < 8; ++kk) {
            bA[kk] = *(const bf16x8*)(p0 + (size_t)kk * 512);
            bB[kk] = *(const bf16x8*)(p1 + (size_t)kk * 512);
        }
    }

    // ---- epilogue1: LN1-fold + SiLU -> Hs, LN2 partials; tables from L2
    {
        float p_s[2][4] = {}, p_q[2][4] = {};
#pragma unroll
        for (int fn = 0; fn < 2; ++fn) {
            int colf = col0 + fn * 16 + l15;
            float vwts = tabF[TB_WTS * 256 + colf];
            float viwt = tabF[TB_IWT * 256 + colf];
            float vsys = tabF[TB_SYS * 256 + colf];
            float vgw1 = tabF[TB_GW1 * 256 + colf];
            float vbwb = tabF[TB_BWB * 256 + colf] + b1[colf];
            const float* tch = &tabF[TB_CH0 * 256 + colf];
#pragma unroll
            for (int fm = 0; fm < 2; ++fm)
#pragma unroll
                for (int j = 0; j < 4; ++j) {
                    int rr = fm * 16 + hi * 4 + j;
                    float fw = acc[fm][fn][j]
                             + fsinv * (rsl[rr] * vwts + viwt)
                             + tch[rsc[rr] * 256] + vsys;
                    float o1 = rrs[rr] * (fw - rmu[rr] * vgw1) + vbwb;
                    float h = o1 / (1.f + __expf(-o1));
                    p_s[fm][j] += h; p_q[fm][j] += h * h;
                    Hs[w * 1280 + rr * 40 + fn * 16 + l15] = f2bf(h);
                }
        }
#pragma unroll
        for (int fm = 0; fm < 2; ++fm)
#pragma unroll
            for (int j = 0; j < 4; ++j) {
                float s = p_s[fm][j], q = p_q[fm][j];
                s += __shfl_xor(s, 1); s += __shfl_xor(s, 2); s += __shfl_xor(s, 4); s += __shfl_xor(s, 8);
                q += __shfl_xor(q, 1); q += __shfl_xor(q, 2); q += __shfl_xor(q, 4); q += __shfl_xor(q, 8);
                if (l15 == 0) {
                    int rr = fm * 16 + hi * 4 + j;
                    ps1[rr * 8 + w] = s; ps2[rr * 8 + w] = q;
                }
            }
    }
    __syncthreads();                                           // B2

    // ---- stats2 (t<32) overlapped with GEMM2
    if (t < 32) {
        f32x4 a = *(f32x4*)&ps1[t * 8], bb = *(f32x4*)&ps1[t * 8 + 4];
        f32x4 cq = *(f32x4*)&ps2[t * 8], dq = *(f32x4*)&ps2[t * 8 + 4];
        float ts = a[0] + a[1] + a[2] + a[3] + bb[0] + bb[1] + bb[2] + bb[3];
        float tq = cq[0] + cq[1] + cq[2] + cq[3] + dq[0] + dq[1] + dq[2] + dq[3];
        float mu2 = ts * (1.f / 256.f);
        float var2 = tq * (1.f / 256.f) - mu2 * mu2;
        rmu2[t] = mu2; rrs2[t] = rsqrtf(var2 + 1e-5f);
    }

    // ---- GEMM2 (K=256): LDS-Hs + in-reg B
    f32x4 acc2[2][2];
#pragma unroll
    for (int fm = 0; fm < 2; ++fm)
#pragma unroll
        for (int fn = 0; fn < 2; ++fn) acc2[fm][fn] = (f32x4){0.f, 0.f, 0.f, 0.f};
#pragma unroll
    for (int kk = 0; kk < 8; ++kk) {
        bf16x8 a0 = *(const bf16x8*)&Hs[kk * 1280 + l15 * 40 + hi * 8];
        bf16x8 a1 = *(const bf16x8*)&Hs[kk * 1280 + (16 + l15) * 40 + hi * 8];
        acc2[0][0] = __builtin_amdgcn_mfma_f32_16x16x32_bf16(a0, bA[kk], acc2[0][0], 0, 0, 0);
        acc2[1][0] = __builtin_amdgcn_mfma_f32_16x16x32_bf16(a1, bA[kk], acc2[1][0], 0, 0, 0);
        acc2[0][1] = __builtin_amdgcn_mfma_f32_16x16x32_bf16(a0, bB[kk], acc2[0][1], 0, 0, 0);
        acc2[1][1] = __builtin_amdgcn_mfma_f32_16x16x32_bf16(a1, bB[kk], acc2[1][1], 0, 0, 0);
    }
    __syncthreads();                                           // B3

    // ---- epilogue2: LN2-fold -> out (tables from L2, issued during GEMM2)
#pragma unroll
    for (int fn = 0; fn < 2; ++fn) {
        int colf = col0 + fn * 16 + l15;
        float vW2G = tabF[TB_W2G * 256 + colf];
        float vB2  = tabF[TB_B2  * 256 + colf] + b2[colf];
#pragma unroll
        for (int fm = 0; fm < 2; ++fm)
#pragma unroll
            for (int j = 0; j < 4; ++j) {
                int rr = fm * 16 + hi * 4 + j;
                float o = rrs2[rr] * (acc2[fm][fn][j] - rmu2[rr] * vW2G) + vB2;
                out[(size_t)(r0 + rr) * 256 + colf] = o;
            }
    }
}

// ================================================================= launch
extern "C" void kernel_launch(void* const* d_in, const int* in_sizes, int n_in,
                              void* d_out, int out_size, void* d_ws, size_t ws_size,
                              hipStream_t stream) {
    const float* x   = (const float*)d_in[0];
    const float* fs  = (const float*)d_in[1];
    const float* ce  = (const float*)d_in[2];
    const float* se  = (const float*)d_in[3];
    const float* g1  = (const float*)d_in[4];
    const float* bb1 = (const float*)d_in[5];
    const float* W1  = (const float*)d_in[6];
    const float* b1  = (const float*)d_in[7];
    const float* g2  = (const float*)d_in[8];
    const float* bb2 = (const float*)d_in[9];
    const float* W2  = (const float*)d_in[10];
    const float* b2  = (const float*)d_in[11];
    const int* sL    = (const int*)d_in[12];
    const int* sC    = (const int*)d_in[13];
    const int* ctm   = (const int*)d_in[14];
    const int* sysid = (const int*)d_in[15];
    float* out = (float*)d_out;

    char* ws = (char*)d_ws;
    u16*   wdt  = (u16*)(ws + 0);          // 131072 B (fragment order)
    u16*   w2t  = (u16*)(ws + 131072);     // 131072 B (fragment order)
    float* tabF = (float*)(ws + 262144);   // 12288 B
    float* scal = (float*)(ws + 274432);   // 64 B

    k_zero<<<dim3(12), dim3(256), 0, stream>>>(tabF);
    k_prep<<<dim3(154), dim3(256), 0, stream>>>(
        W1, W2, g1, bb1, g2, bb2, ce, se, ctm, sysid, wdt, w2t, tabF, scal);
    k_main<<<dim3(NROWS / 32), dim3(512), 0, stream>>>(
        x, fs, sL, sC, wdt, w2t, tabF, scal, b1, b2, out);
}